// Round 11
// baseline (136.726 us; speedup 1.0000x reference)
//
#include <hip/hip_runtime.h>

// Graph transformer block, multiplicative adjacency masking.
// v11: h-space reformulation to HALVE gather traffic:
//   s_ij = Q'_i . h_j  with  Q' = h @ (Wq^T Wk)
//   num_i = (hsum + sum_edges e_ij h_j) @ Wv^T ;  out = num / (N + den)
// Per edge we gather ONLY h_j (512 B bf16) which feeds both dot and axpy.
// Wv is applied once at the end as a dense GEMM with 1/(N+den) epilogue.

#define NN  8192
#define DIM 256
#define SCALE 0.0625f   // 1/sqrt(256)
#define CAP 32          // per-(row,eighth) edge capacity

typedef __attribute__((ext_vector_type(8))) short short8;
typedef __attribute__((ext_vector_type(4))) float f32x4;
typedef __attribute__((ext_vector_type(4))) unsigned short u16x4;

__device__ __forceinline__ unsigned short f2bf(float f) {
    union { float f; unsigned u; } v; v.f = f;
    unsigned u = v.u;
    unsigned r = (u + 0x7fffu + ((u >> 16) & 1u)) >> 16;   // RNE
    return (unsigned short)r;
}
__device__ __forceinline__ float bf2f(unsigned short s) {
    union { unsigned u; float f; } v; v.u = ((unsigned)s) << 16;
    return v.f;
}

// ---------------------------------------------------------------- prep: fp32 -> bf16
__global__ __launch_bounds__(256) void prep_kernel(
    const float* __restrict__ h, const float* __restrict__ Wq,
    const float* __restrict__ Wk, const float* __restrict__ Wv,
    unsigned short* __restrict__ h_bf, unsigned short* __restrict__ w_bf)
{
    int b = blockIdx.x, t = threadIdx.x;
    if (b < 2048) {
        int idx = (b * 256 + t) * 4;               // h: 2,097,152 elems
        float4 v = *(const float4*)(h + idx);
        ushort4 o; o.x = f2bf(v.x); o.y = f2bf(v.y); o.z = f2bf(v.z); o.w = f2bf(v.w);
        *(ushort4*)(h_bf + idx) = o;
    } else {
        int idx = ((b - 2048) * 256 + t) * 4;      // W: 196,608 elems (3 x 65536)
        int w = idx >> 16;
        int offn = idx & 65535;
        const float* src = (w == 0) ? Wq : (w == 1) ? Wk : Wv;
        float4 v = *(const float4*)(src + offn);
        ushort4 o; o.x = f2bf(v.x); o.y = f2bf(v.y); o.z = f2bf(v.z); o.w = f2bf(v.w);
        *(ushort4*)(w_bf + idx) = o;
    }
}

// ---------------------------------------------------------------- Mt[b][a] = sum_o Wq[o][a]*Wk[o][b]
// (Mt is M^T stored row-major so the Q' GEMM can use the proj pattern.)
__global__ __launch_bounds__(256) void mgen(
    const unsigned short* __restrict__ w_bf, unsigned short* __restrict__ Mt)
{
    __shared__ float s_col[256];
    const int a = blockIdx.x, t = threadIdx.x;
    s_col[t] = bf2f(w_bf[t * 256 + a]);                 // Wq[t][a]
    __syncthreads();
    const unsigned short* Wk = w_bf + 65536;
    float acc = 0.f;
    for (int o = 0; o < 256; ++o)
        acc = fmaf(s_col[o], bf2f(Wk[o * 256 + t]), acc);
    Mt[(size_t)t * 256 + a] = f2bf(acc);
}

// ---------------------------------------------------------------- GEMM: C[i][b] = sum_a A[i][a] * B[b][a]
// A bf16 [8192][256], B bf16 [256][256]. p==0-style writer to f32.
__global__ __launch_bounds__(256) void gemm_q(
    const unsigned short* __restrict__ A, const unsigned short* __restrict__ B,
    float* __restrict__ C)
{
    __shared__ unsigned short sB[256][40];
    const int mb = blockIdx.x;
    const int tid = threadIdx.x, wave = tid >> 6, lane = tid & 63;

    f32x4 acc[16];
#pragma unroll
    for (int f = 0; f < 16; ++f) acc[f] = (f32x4)(0.0f);

    const int arow = mb * 64 + wave * 16 + (lane & 15);
    const int ko   = (lane >> 4) * 8;

    for (int kk = 0; kk < 256; kk += 32) {
        __syncthreads();
        {
            const uint4* src = (const uint4*)(B + tid * 256 + kk);
            uint4* dst = (uint4*)(&sB[tid][0]);
            dst[0] = src[0]; dst[1] = src[1]; dst[2] = src[2]; dst[3] = src[3];
        }
        __syncthreads();
        short8 a = *(const short8*)(A + (size_t)arow * 256 + kk + ko);
#pragma unroll
        for (int f = 0; f < 16; ++f) {
            short8 b = *(const short8*)(&sB[f * 16 + (lane & 15)][ko]);
            acc[f] = __builtin_amdgcn_mfma_f32_16x16x32_bf16(a, b, acc[f], 0, 0, 0);
        }
    }

    const int orow = mb * 64 + wave * 16 + ((lane >> 4) << 2);
    const int ocol = lane & 15;
#pragma unroll
    for (int f = 0; f < 16; ++f)
#pragma unroll
        for (int r = 0; r < 4; ++r)
            C[(size_t)(orow + r) * 256 + f * 16 + ocol] = acc[f][r];
}

// ---------------------------------------------------------------- out GEMM: out[i][o] = (sum_k T[i][k]*Wv[o][k]) * dfac[i]
__global__ __launch_bounds__(256) void gemm_out(
    const unsigned short* __restrict__ Tb, const unsigned short* __restrict__ Wv,
    const float* __restrict__ dfac, float* __restrict__ out)
{
    __shared__ unsigned short sB[256][40];
    const int mb = blockIdx.x;
    const int tid = threadIdx.x, wave = tid >> 6, lane = tid & 63;

    f32x4 acc[16];
#pragma unroll
    for (int f = 0; f < 16; ++f) acc[f] = (f32x4)(0.0f);

    const int arow = mb * 64 + wave * 16 + (lane & 15);
    const int ko   = (lane >> 4) * 8;

    for (int kk = 0; kk < 256; kk += 32) {
        __syncthreads();
        {
            const uint4* src = (const uint4*)(Wv + tid * 256 + kk);
            uint4* dst = (uint4*)(&sB[tid][0]);
            dst[0] = src[0]; dst[1] = src[1]; dst[2] = src[2]; dst[3] = src[3];
        }
        __syncthreads();
        short8 a = *(const short8*)(Tb + (size_t)arow * 256 + kk + ko);
#pragma unroll
        for (int f = 0; f < 16; ++f) {
            short8 b = *(const short8*)(&sB[f * 16 + (lane & 15)][ko]);
            acc[f] = __builtin_amdgcn_mfma_f32_16x16x32_bf16(a, b, acc[f], 0, 0, 0);
        }
    }

    const int orow = mb * 64 + wave * 16 + ((lane >> 4) << 2);
    const int ocol = lane & 15;
    float df0 = dfac[orow + 0], df1 = dfac[orow + 1];
    float df2 = dfac[orow + 2], df3 = dfac[orow + 3];
#pragma unroll
    for (int f = 0; f < 16; ++f) {
        out[(size_t)(orow + 0) * 256 + f * 16 + ocol] = acc[f][0] * df0;
        out[(size_t)(orow + 1) * 256 + f * 16 + ocol] = acc[f][1] * df1;
        out[(size_t)(orow + 2) * 256 + f * 16 + ocol] = acc[f][2] * df2;
        out[(size_t)(orow + 3) * 256 + f * 16 + ocol] = acc[f][3] * df3;
    }
}

// ---------------------------------------------------------------- hsum = column sums of h (bf16)
__global__ __launch_bounds__(256) void hsum_partial(
    const unsigned short* __restrict__ hb, float* __restrict__ partial)
{
    int b = blockIdx.x, t = threadIdx.x;
    float s = 0.0f;
    for (int r = 0; r < 64; ++r)
        s += bf2f(hb[(size_t)(b * 64 + r) * 256 + t]);
    partial[b * 256 + t] = s;
}
__global__ __launch_bounds__(256) void hsum_final(
    const float* __restrict__ partial, float* __restrict__ hsum)
{
    int t = threadIdx.x;
    float s = 0.0f;
    for (int b = 0; b < 128; ++b) s += partial[b * 256 + t];
    hsum[t] = s;
}

// ---------------------------------------------------------------- sparse pass: 1 wave = (row i, eighth e)
// grid 32768 x 128, e-major. Per wave: nt-load 4 KB adj slice, ballot-compact
// (~10 edges), then per round of 4 edges gather 4 h_j rows (512 B each, shared
// by dot AND axpy): 4-dim/lane dots + 6-step xor reduce (all lanes get d),
// e = exp(s)-1 computed in every lane (no broadcast), 16-fma axpy.
__global__ __launch_bounds__(128) void attn_e(
    const float* __restrict__ adj, const float* __restrict__ Q,
    const unsigned short* __restrict__ hb,
    unsigned short* __restrict__ pnum, float* __restrict__ pden)
{
    __shared__ unsigned short s_idx[2][CAP];

    const int e    = blockIdx.x >> 12;           // 0..7
    const int i    = ((blockIdx.x & 4095) << 1) + (threadIdx.x >> 6);
    const int lane = threadIdx.x & 63;
    const int w    = threadIdx.x >> 6;
    const unsigned long long lt = (1ull << lane) - 1ull;

    // adj panel slice: 1024 floats = 4 x f32x4 per lane, nontemporal
    const f32x4* arow4 = (const f32x4*)(adj + (size_t)i * NN + e * 1024);
    f32x4 a0 = __builtin_nontemporal_load(arow4 + lane);
    f32x4 a1 = __builtin_nontemporal_load(arow4 + 64 + lane);
    f32x4 a2 = __builtin_nontemporal_load(arow4 + 128 + lane);
    f32x4 a3 = __builtin_nontemporal_load(arow4 + 192 + lane);

    // Q' chunk: dims lane*4..+3 (one float4 per lane)
    f32x4 q = *(const f32x4*)(Q + (size_t)i * DIM + lane * 4);

    // ballot compaction into this wave's LDS segment
    const int jbase = e * 1024;
    int off = 0;
#pragma unroll
    for (int s = 0; s < 4; ++s) {
        f32x4 av = (s == 0) ? a0 : (s == 1) ? a1 : (s == 2) ? a2 : a3;
        const int colbase = jbase + (s * 64 + lane) * 4;
#pragma unroll
        for (int c = 0; c < 4; ++c) {
            bool nz = (av[c] != 0.0f);
            unsigned long long m = __ballot(nz);
            if (nz) {
                int pos = off + __popcll(m & lt);
                if (pos < CAP) s_idx[w][pos] = (unsigned short)(colbase + c);
            }
            off += __popcll(m);
        }
    }
    const int cnt = (off < CAP) ? off : CAP;     // wave-uniform

    float acc0 = 0.f, acc1 = 0.f, acc2 = 0.f, acc3 = 0.f, den = 0.f;
    const int rounds = (cnt + 3) >> 2;

#pragma unroll 2
    for (int r = 0; r < rounds; ++r) {
        const int kb0 = r * 4;
        int jg0 = (kb0 + 0 < cnt) ? (int)s_idx[w][kb0 + 0] : 0;
        int jg1 = (kb0 + 1 < cnt) ? (int)s_idx[w][kb0 + 1] : 0;
        int jg2 = (kb0 + 2 < cnt) ? (int)s_idx[w][kb0 + 2] : 0;
        int jg3 = (kb0 + 3 < cnt) ? (int)s_idx[w][kb0 + 3] : 0;

        // 4 h_j rows, 8 B/lane each (dims lane*4..+3) — feeds dot AND axpy
        ushort4 v0 = *(const ushort4*)(hb + (size_t)jg0 * DIM + lane * 4);
        ushort4 v1 = *(const ushort4*)(hb + (size_t)jg1 * DIM + lane * 4);
        ushort4 v2 = *(const ushort4*)(hb + (size_t)jg2 * DIM + lane * 4);
        ushort4 v3 = *(const ushort4*)(hb + (size_t)jg3 * DIM + lane * 4);

        float f00 = bf2f(v0.x), f01 = bf2f(v0.y), f02 = bf2f(v0.z), f03 = bf2f(v0.w);
        float f10 = bf2f(v1.x), f11 = bf2f(v1.y), f12 = bf2f(v1.z), f13 = bf2f(v1.w);
        float f20 = bf2f(v2.x), f21 = bf2f(v2.y), f22 = bf2f(v2.z), f23 = bf2f(v2.w);
        float f30 = bf2f(v3.x), f31 = bf2f(v3.y), f32_ = bf2f(v3.z), f33 = bf2f(v3.w);

        float d0 = q[0] * f00; d0 = fmaf(q[1], f01, d0); d0 = fmaf(q[2], f02, d0); d0 = fmaf(q[3], f03, d0);
        float d1 = q[0] * f10; d1 = fmaf(q[1], f11, d1); d1 = fmaf(q[2], f12, d1); d1 = fmaf(q[3], f13, d1);
        float d2 = q[0] * f20; d2 = fmaf(q[1], f21, d2); d2 = fmaf(q[2], f22, d2); d2 = fmaf(q[3], f23, d2);
        float d3 = q[0] * f30; d3 = fmaf(q[1], f31, d3); d3 = fmaf(q[2], f32_, d3); d3 = fmaf(q[3], f33, d3);

#pragma unroll
        for (int m = 1; m < 64; m <<= 1) {
            d0 += __shfl_xor(d0, m);
            d1 += __shfl_xor(d1, m);
            d2 += __shfl_xor(d2, m);
            d3 += __shfl_xor(d3, m);
        }

        float e0 = (kb0 + 0 < cnt) ? (__expf(SCALE * d0) - 1.0f) : 0.0f;
        float e1 = (kb0 + 1 < cnt) ? (__expf(SCALE * d1) - 1.0f) : 0.0f;
        float e2 = (kb0 + 2 < cnt) ? (__expf(SCALE * d2) - 1.0f) : 0.0f;
        float e3 = (kb0 + 3 < cnt) ? (__expf(SCALE * d3) - 1.0f) : 0.0f;
        den += (e0 + e1) + (e2 + e3);

        acc0 = fmaf(e0, f00, acc0); acc1 = fmaf(e0, f01, acc1);
        acc2 = fmaf(e0, f02, acc2); acc3 = fmaf(e0, f03, acc3);
        acc0 = fmaf(e1, f10, acc0); acc1 = fmaf(e1, f11, acc1);
        acc2 = fmaf(e1, f12, acc2); acc3 = fmaf(e1, f13, acc3);
        acc0 = fmaf(e2, f20, acc0); acc1 = fmaf(e2, f21, acc1);
        acc2 = fmaf(e2, f22, acc2); acc3 = fmaf(e2, f23, acc3);
        acc0 = fmaf(e3, f30, acc0); acc1 = fmaf(e3, f31, acc1);
        acc2 = fmaf(e3, f32_, acc2); acc3 = fmaf(e3, f33, acc3);
    }

    u16x4 o = { f2bf(acc0), f2bf(acc1), f2bf(acc2), f2bf(acc3) };
    __builtin_nontemporal_store(o, (u16x4*)(pnum + ((size_t)i * 8 + e) * 256 + lane * 4));
    if (lane == 0) pden[(size_t)i * 8 + e] = den;
}

// ---------------------------------------------------------------- tfinal: T row (bf16) + 1/(N+den)
__global__ __launch_bounds__(256) void tfinal(
    const unsigned short* __restrict__ pnum, const float* __restrict__ pden,
    const float* __restrict__ hsum, unsigned short* __restrict__ Tb,
    float* __restrict__ dfac)
{
    const int i = blockIdx.x, t = threadIdx.x;
    float num = hsum[t], den = 0.0f;
#pragma unroll
    for (int x = 0; x < 8; ++x) {
        num += bf2f(pnum[((size_t)i * 8 + x) * 256 + t]);
        den += pden[(size_t)i * 8 + x];
    }
    Tb[(size_t)i * 256 + t] = f2bf(num);
    if (t == 0) dfac[i] = 1.0f / (8192.0f + den);
}

// ---------------------------------------------------------------- host
extern "C" void kernel_launch(void* const* d_in, const int* in_sizes, int n_in,
                              void* d_out, int out_size, void* d_ws, size_t ws_size,
                              hipStream_t stream)
{
    const float* adj = (const float*)d_in[0];
    const float* h   = (const float*)d_in[1];
    const float* Wq  = (const float*)d_in[2];
    const float* Wk  = (const float*)d_in[3];
    const float* Wv  = (const float*)d_in[4];
    float* out = (float*)d_out;

    char* ws = (char*)d_ws;
    size_t off = 0;
    unsigned short* p_hbf = (unsigned short*)(ws + off); off += (size_t)NN * DIM * 2;
    unsigned short* p_wbf = (unsigned short*)(ws + off); off += (size_t)3 * DIM * DIM * 2;
    off = (off + 1023) & ~(size_t)1023;
    unsigned short* p_Mt  = (unsigned short*)(ws + off); off += (size_t)DIM * DIM * 2;
    float*          p_Q   = (float*)(ws + off);          off += (size_t)NN * DIM * 4;
    float*          p_par = (float*)(ws + off);          off += (size_t)128 * DIM * 4;
    float*          p_hs  = (float*)(ws + off);          off += DIM * 4;
    unsigned short* p_pn  = (unsigned short*)(ws + off); off += (size_t)NN * 8 * 256 * 2;  // 33.6 MB
    float*          p_pd  = (float*)(ws + off);          off += (size_t)NN * 8 * 4;
    unsigned short* p_Tb  = (unsigned short*)(ws + off); off += (size_t)NN * DIM * 2;
    float*          p_df  = (float*)(ws + off);          off += (size_t)NN * 4;
    (void)ws_size; (void)in_sizes; (void)n_in; (void)out_size;

    prep_kernel<<<2240, 256, 0, stream>>>(h, Wq, Wk, Wv, p_hbf, p_wbf);
    mgen<<<256, 256, 0, stream>>>(p_wbf, p_Mt);
    gemm_q<<<128, 256, 0, stream>>>(p_hbf, p_Mt, p_Q);
    hsum_partial<<<128, 256, 0, stream>>>(p_hbf, p_par);
    hsum_final<<<1, 256, 0, stream>>>(p_par, p_hs);
    attn_e<<<NN * 8 / 2, 128, 0, stream>>>(adj, p_Q, p_hbf, p_pn, p_pd);
    tfinal<<<NN, 256, 0, stream>>>(p_pn, p_pd, p_hs, p_Tb, p_df);
    gemm_out<<<128, 256, 0, stream>>>(p_Tb, p_wbf + 2 * 65536, p_df, out);
}